// Round 9
// baseline (1575.846 us; speedup 1.0000x reference)
//
#include <hip/hip_runtime.h>
#include <cstdint>
#include <cstddef>

#define LOG2E 1.4426950408889634f

using f32x4 = __attribute__((ext_vector_type(4))) float;
using s16x8 = __attribute__((ext_vector_type(8))) short;
using s16x4 = __attribute__((ext_vector_type(4))) short;

__device__ __forceinline__ short f2bf(float f){
  unsigned u = __builtin_bit_cast(unsigned, f);
  u = u + 0x7FFFu + ((u >> 16) & 1u);          // RNE
  return (short)(u >> 16);
}
__device__ __forceinline__ float bf2f(short s){
  unsigned u = ((unsigned)(unsigned short)s) << 16;
  return __builtin_bit_cast(float, u);
}
__device__ __forceinline__ float fexp2(float x){ return __builtin_amdgcn_exp2f(x); }
__device__ __forceinline__ float frcp (float x){ return __builtin_amdgcn_rcpf(x); }
__device__ __forceinline__ float sigmoid_f(float x){
  return frcp(1.f + fexp2(-LOG2E * x));
}
__device__ __forceinline__ float tanh_f(float x){
  return 1.f - 2.f * frcp(fexp2(2.f * LOG2E * x) + 1.f);
}

#define MFMA16(a,b,c) __builtin_amdgcn_mfma_f32_16x16x32_bf16(a,b,c,0,0,0)

// ---------------- GEMM: C[M,N] = A[M,K] @ W[N,K]^T (+bias), bf16 MFMA ----------------
__global__ __launch_bounds__(256) void gemm_k(
    const float* __restrict__ A, const float* __restrict__ W,
    const float* __restrict__ bias, void* __restrict__ Cout,
    int M, int N, int K, int outBf16)
{
  __shared__ short As[64*40];
  __shared__ short Ws[64*40];
  const int tid  = threadIdx.x;
  const int lane = tid & 63;
  const int wave = tid >> 6;
  const int wm   = wave >> 1, wn = wave & 1;
  const int c    = lane & 15, rg = lane >> 4;
  const int bm   = blockIdx.y * 64, bn = blockIdx.x * 64;
  const int K4   = K >> 2;
  const int nkt  = (K + 31) >> 5;
  f32x4 acc[2][2] = {};
  for (int kt = 0; kt < nkt; ++kt){
    #pragma unroll
    for (int h = 0; h < 2; ++h){
      int idx = tid + h*256;
      int row = idx >> 3, q = idx & 7;
      int kq  = kt*8 + q;
      f32x4 av = {0.f,0.f,0.f,0.f}, wv4 = {0.f,0.f,0.f,0.f};
      if (kq < K4){
        av  = *(const f32x4*)(A + (size_t)(bm+row)*K + (size_t)kq*4);
        wv4 = *(const f32x4*)(W + (size_t)(bn+row)*K + (size_t)kq*4);
      }
      s16x4 ap, wp;
      #pragma unroll
      for (int i = 0; i < 4; ++i){ ap[i] = f2bf(av[i]); wp[i] = f2bf(wv4[i]); }
      *(s16x4*)&As[row*40 + q*4] = ap;
      *(s16x4*)&Ws[row*40 + q*4] = wp;
    }
    __syncthreads();
    s16x8 af[2], bf[2];
    #pragma unroll
    for (int mi = 0; mi < 2; ++mi) af[mi] = *(const s16x8*)&As[(wm*32 + mi*16 + c)*40 + rg*8];
    #pragma unroll
    for (int ni = 0; ni < 2; ++ni) bf[ni] = *(const s16x8*)&Ws[(wn*32 + ni*16 + c)*40 + rg*8];
    #pragma unroll
    for (int mi = 0; mi < 2; ++mi)
      #pragma unroll
      for (int ni = 0; ni < 2; ++ni)
        acc[mi][ni] = MFMA16(af[mi], bf[ni], acc[mi][ni]);
    __syncthreads();
  }
  #pragma unroll
  for (int mi = 0; mi < 2; ++mi)
    #pragma unroll
    for (int ni = 0; ni < 2; ++ni)
      #pragma unroll
      for (int i = 0; i < 4; ++i){
        int row = bm + wm*32 + mi*16 + rg*4 + i;
        int col = bn + wn*32 + ni*16 + c;
        float v = acc[mi][ni][i] + (bias ? bias[col] : 0.f);
        if (outBf16) ((short*)Cout)[(size_t)row*N + col] = f2bf(v);
        else         ((float*)Cout)[(size_t)row*N + col] = v;
      }
}

// ---------------- GRU scan: one block per (chain, direction), 16 waves ----------------
// Wave w owns output cols j = w*16 + c for ALL 3 gates: wfrag[3][8] = 96 VGPR/wave.
// amdgpu_waves_per_eu(4,4): exactly 4 waves/SIMD (one 16-wave block/CU) -> 128-VGPR
// cap, so the weight set is register-resident across the CU (16 x 24KB = full Wh).
// Bias applied in gate phase from LDS (no regs live across MFMA loop). xp double-
// buffered in LDS via global_load_lds prefetch; h fp32 in regs; bf16 h XOR-swizzled LDS.
__global__ __launch_bounds__(1024) __attribute__((amdgpu_waves_per_eu(4, 4)))
void gru_scan_k(
    int nA, int TA, int sBA, int bMA,
    const short* __restrict__ xpfA, const short* __restrict__ xpbA, float* __restrict__ outA,
    int TB, int sBB, int bMB,
    const short* __restrict__ xpfB, const short* __restrict__ xpbB, float* __restrict__ outB,
    const float* __restrict__ Whf, const float* __restrict__ Whb,
    const float* __restrict__ bhf, const float* __restrict__ bhb)
{
  __shared__ short h_bf[16*256];     // (b,k) at b*256 + (k ^ ((b&7)<<3))
  __shared__ short xp_s[2][16*768];  // double-buffered [b][n] bf16
  __shared__ float bh_s[768];

  const int tid  = threadIdx.x;
  const int w    = tid >> 6;          // 0..15
  const int lane = tid & 63;
  const int c    = lane & 15;
  const int rg   = lane >> 4;
  const int j    = w*16 + c;          // output column 0..255

  int T, strideB, baseRow, dir;
  const short* xp; float* outp;
  const float* Wh; const float* bh;
  {
    int bid = blockIdx.x;
    if (bid < nA){
      int idx = bid >> 1; dir = bid & 1;
      T = TA; strideB = sBA; baseRow = idx * bMA;
      xp = dir ? xpbA : xpfA; outp = outA;
    } else {
      int jj = bid - nA; int idx = jj >> 1; dir = jj & 1;
      T = TB; strideB = sBB; baseRow = idx * bMB;
      xp = dir ? xpbB : xpfB; outp = outB;
    }
    Wh = dir ? Whb : Whf;
    bh = dir ? bhb : bhf;
  }

  {
    s16x4 z4 = {0,0,0,0};
    *(s16x4*)&h_bf[tid*4] = z4;             // 1024 threads x 4 shorts = 4096
  }
  if (tid < 768) bh_s[tid] = bh[tid];

  // Wh -> bf16 register fragments: 3 gates x 8 kb x 4 VGPR = 96 VGPR (one-time)
  s16x8 wfrag[3][8];
  #pragma unroll
  for (int gate = 0; gate < 3; ++gate){
    const float* wr = Wh + (size_t)(gate*256 + j)*256 + rg*8;
    #pragma unroll
    for (int kb = 0; kb < 8; ++kb){
      f32x4 lo = *(const f32x4*)(wr + kb*32);
      f32x4 hi = *(const f32x4*)(wr + kb*32 + 4);
      s16x8 f;
      #pragma unroll
      for (int i = 0; i < 4; ++i){ f[i] = f2bf(lo[i]); f[4+i] = f2bf(hi[i]); }
      wfrag[gate][kb] = f;
    }
  }

  auto stage = [&](int tt_, int buf){
    #pragma unroll
    for (int i2 = 0; i2 < 2; ++i2){
      if (i2 == 0 || tid < 512){            // 1536 8-short units, wave-uniform split
        int idx8 = tid + 1024*i2;
        int row  = idx8 / 96;
        int u    = idx8 - row*96;
        const short* src = xp + (size_t)(baseRow + row*strideB + tt_)*768 + u*8;
        __builtin_amdgcn_global_load_lds((const __attribute__((address_space(1))) void*)src,
                                         (__attribute__((address_space(3))) void*)&xp_s[buf][idx8*8],
                                         16, 0, 0);
      }
    }
  };

  float hprev[4] = {};
  stage(dir ? (T - 1) : 0, 0);
  __syncthreads();                          // xp buf0 ready; h_bf zeros + bh_s visible

  for (int t = 0; t < T; ++t){
    const int cur = t & 1;
    if (t + 1 < T) stage(dir ? (T - 2 - t) : (t + 1), cur ^ 1);   // prefetch next step
    const int tt = dir ? (T - 1 - t) : t;

    f32x4 ar = {0.f,0.f,0.f,0.f}, az = {0.f,0.f,0.f,0.f}, an = {0.f,0.f,0.f,0.f};
    #pragma unroll
    for (int kb = 0; kb < 8; ++kb){
      const int k0 = kb*32 + rg*8;
      const s16x8 a = *(const s16x8*)&h_bf[c*256 + (k0 ^ ((c & 7) << 3))];
      ar = MFMA16(a, wfrag[0][kb], ar);
      az = MFMA16(a, wfrag[1][kb], az);
      an = MFMA16(a, wfrag[2][kb], an);
    }
    const float bhr = bh_s[j], bhz = bh_s[256 + j], bhn = bh_s[512 + j];
    const short* xrow = &xp_s[cur][0];
    #pragma unroll
    for (int i = 0; i < 4; ++i){
      const int b = rg*4 + i;               // D: row=(l>>4)*4+reg = batch
      const float xr = bf2f(xrow[b*768 + j]);
      const float xz = bf2f(xrow[b*768 + 256 + j]);
      const float xn = bf2f(xrow[b*768 + 512 + j]);
      float r = sigmoid_f(ar[i] + bhr + xr);
      float z = sigmoid_f(az[i] + bhz + xz);
      float n = tanh_f(xn + r*(an[i] + bhn));
      float h = n + z*(hprev[i] - n);
      hprev[i] = h;
      outp[(size_t)(baseRow + b*strideB + tt)*512 + (size_t)dir*256 + j] = h;
    }
    __syncthreads();                        // all h_bf reads done (also drains prefetch vmcnt)
    #pragma unroll
    for (int i = 0; i < 4; ++i){
      const int b = rg*4 + i;
      h_bf[b*256 + (j ^ ((b & 7) << 3))] = f2bf(hprev[i]);
    }
    __syncthreads();                        // new h visible to all waves
  }
}

// ---------------- Bahdanau energies: e[o,b,q,c] = sum_h tanh(oq+ck)*v ----------------
__global__ __launch_bounds__(256) void energy_k(
    const float* __restrict__ oq, const float* __restrict__ ck,
    const float* __restrict__ v, float* __restrict__ e)
{
  __shared__ float oqs[4][256];
  __shared__ float vs[256];
  const int bid = blockIdx.x;          // 1280 = 5 o * 16 b * 16 qg
  const int o  = bid >> 8;
  const int b  = (bid >> 4) & 15;
  const int qg = bid & 15;
  const int tid = threadIdx.x;
  const int wv = tid >> 6, lane = tid & 63;
  const int q = qg*4 + wv;
  vs[tid] = v[tid];
  const float* oqrow = oq + (size_t)((b*5 + o)*64 + q)*256;
  #pragma unroll
  for (int i = 0; i < 4; ++i) oqs[wv][lane + i*64] = oqrow[lane + i*64];
  __syncthreads();
  float acc0 = 0.f, acc1 = 0.f;
  const float* ckb = ck + (size_t)b*128*256;
  for (int h = 0; h < 256; ++h){
    float t  = oqs[wv][h];
    float vh = vs[h];
    acc0 += tanh_f(t + ckb[(size_t)lane*256 + h]) * vh;
    acc1 += tanh_f(t + ckb[(size_t)(lane+64)*256 + h]) * vh;
  }
  const size_t ebase = (size_t)((o*16 + b)*64 + q)*128;
  e[ebase + lane]      = acc0;
  e[ebase + lane + 64] = acc1;
}

// softmax over q (64) + a_ctx[o,b,c,h] = sum_q w_q * oq[b,o,q,h]
__global__ __launch_bounds__(256) void actx_k(
    const float* __restrict__ e, const float* __restrict__ oq, float* __restrict__ a_ctx)
{
  __shared__ float wq[64];
  const int bid = blockIdx.x;          // 10240 = 5 o * 16 b * 128 c
  const int o  = bid >> 11;
  const int b  = (bid >> 7) & 15;
  const int cc = bid & 127;
  const int tid = threadIdx.x;
  if (tid < 64){
    float x = e[((size_t)((o*16 + b)*64 + tid))*128 + cc];
    float mx = x;
    #pragma unroll
    for (int off = 32; off; off >>= 1) mx = fmaxf(mx, __shfl_xor(mx, off));
    float p = fexp2((x - mx)*LOG2E);
    float sm = p;
    #pragma unroll
    for (int off = 32; off; off >>= 1) sm += __shfl_xor(sm, off);
    wq[tid] = p * frcp(sm);
  }
  __syncthreads();
  float acc = 0.f;
  const float* oqb = oq + ((size_t)(b*320 + o*64))*256 + tid;
  #pragma unroll 4
  for (int q = 0; q < 64; ++q) acc += wq[q] * oqb[(size_t)q*256];
  a_ctx[((size_t)((o*16 + b)*128 + cc))*256 + tid] = acc;
}

// softmax over c (128) + a_opt[o,b,q,h] = sum_c w_c * ck[b,c,h]
__global__ __launch_bounds__(256) void aopt_k(
    const float* __restrict__ e, const float* __restrict__ ck, float* __restrict__ a_opt)
{
  __shared__ float wc[128];
  __shared__ float red[4];
  const int bid = blockIdx.x;          // 5120 = 5 o * 16 b * 64 q
  const int o = bid >> 10;
  const int b = (bid >> 6) & 15;
  const int q = bid & 63;
  const int tid = threadIdx.x, lane = tid & 63, wv = tid >> 6;
  const float* er = e + ((size_t)((o*16 + b)*64 + q))*128;
  float x = (tid < 128) ? er[tid] : -3.0e38f;
  float mx = x;
  #pragma unroll
  for (int off = 32; off; off >>= 1) mx = fmaxf(mx, __shfl_xor(mx, off));
  if (lane == 0 && wv < 2) red[wv] = mx;
  __syncthreads();
  float gm = fmaxf(red[0], red[1]);
  float p = (tid < 128) ? fexp2((x - gm)*LOG2E) : 0.f;
  float sm = p;
  #pragma unroll
  for (int off = 32; off; off >>= 1) sm += __shfl_xor(sm, off);
  if (lane == 0 && wv < 2) red[2 + wv] = sm;
  __syncthreads();
  float tot = red[2] + red[3];
  if (tid < 128) wc[tid] = p * frcp(tot);
  __syncthreads();
  float acc = 0.f;
  const float* ckb = ck + (size_t)b*128*256 + tid;
  #pragma unroll 4
  for (int cc = 0; cc < 128; ++cc) acc += wc[cc] * ckb[(size_t)cc*256];
  a_opt[((size_t)((o*16 + b)*64 + q))*256 + tid] = acc;
}

// mean over T rows of 512: 8 independent accumulators -> 8 loads in flight
__global__ __launch_bounds__(512) void mean_k(
    const float* __restrict__ src, float* __restrict__ dst, int T)
{
  const int r = blockIdx.x;            // 80 = (o*16+b)
  const int f = threadIdx.x;
  const float* s = src + (size_t)r*T*512 + f;
  float a0=0.f,a1=0.f,a2=0.f,a3=0.f,a4=0.f,a5=0.f,a6=0.f,a7=0.f;
  for (int t = 0; t < T; t += 8){
    a0 += s[(size_t)(t+0)*512]; a1 += s[(size_t)(t+1)*512];
    a2 += s[(size_t)(t+2)*512]; a3 += s[(size_t)(t+3)*512];
    a4 += s[(size_t)(t+4)*512]; a5 += s[(size_t)(t+5)*512];
    a6 += s[(size_t)(t+6)*512]; a7 += s[(size_t)(t+7)*512];
  }
  float acc = ((a0+a1)+(a2+a3)) + ((a4+a5)+(a6+a7));
  dst[(size_t)r*512 + f] = acc / (float)T;
}

__global__ __launch_bounds__(512) void final_k(
    const float* __restrict__ mc, const float* __restrict__ mo, float* __restrict__ out)
{
  __shared__ float lg[80];
  const int tid = threadIdx.x;
  const int wv = tid >> 6, lane = tid & 63;
  #pragma unroll
  for (int it = 0; it < 10; ++it){
    const int p = wv + it*8;
    const float* a = mc + (size_t)p*512;
    const float* b = mo + (size_t)p*512;
    float d = 0.f, na = 0.f, nb = 0.f;
    #pragma unroll
    for (int i = 0; i < 8; ++i){
      float x = a[lane + 64*i], y = b[lane + 64*i];
      d += x*y; na += x*x; nb += y*y;
    }
    #pragma unroll
    for (int off = 32; off; off >>= 1){
      d += __shfl_xor(d, off); na += __shfl_xor(na, off); nb += __shfl_xor(nb, off);
    }
    if (lane == 0){
      float den = fmaxf(sqrtf(na), 1e-8f) * fmaxf(sqrtf(nb), 1e-8f);
      lg[p] = d / den;
    }
  }
  __syncthreads();
  if (tid < 16){
    float l[5];
    float mx = -3.0e38f;
    #pragma unroll
    for (int o = 0; o < 5; ++o){ l[o] = lg[o*16 + tid]; mx = fmaxf(mx, l[o]); }
    float s = 0.f;
    #pragma unroll
    for (int o = 0; o < 5; ++o){ l[o] = fexp2((l[o]-mx)*LOG2E); s += l[o]; }
    #pragma unroll
    for (int o = 0; o < 5; ++o) out[tid*5 + o] = l[o] / s;
  }
}

// ---------------- workspace layout (bytes, all offsets 256-aligned) ----------------
static constexpr size_t OFF_XP_CTX_F  = 0;          // 2048*768*2  = 3,145,728
static constexpr size_t OFF_XP_CTX_B  = 3145728;
static constexpr size_t OFF_XP_OPT_F  = 6291456;    // 5120*768*2  = 7,864,320
static constexpr size_t OFF_XP_OPT_B  = 14155776;
static constexpr size_t OFF_AXP_CTX_F = 0;          // 10240*768*2 = 15,728,640
static constexpr size_t OFF_AXP_CTX_B = 15728640;
static constexpr size_t OFF_AXP_OPT_F = 31457280;   // 5120*768*2
static constexpr size_t OFF_AXP_OPT_B = 39321600;
static constexpr size_t REGION_B      = 47185920;
static constexpr size_t OFF_CTX_ENC   = REGION_B;               // 2048*512*4
static constexpr size_t OFF_OPT_ENC   = REGION_B + 4194304;     // 5120*512*4
static constexpr size_t OFF_ATT_ENC_C = REGION_B;               // 10240*512*4
static constexpr size_t OFF_ATT_ENC_O = REGION_B + 20971520;    // 5120*512*4
static constexpr size_t OFF_CTX_KEY   = 78643200;   // 2048*256*4
static constexpr size_t OFF_OPT_Q     = 80740352;   // 5120*256*4
static constexpr size_t OFF_E         = 85983232;   // 5*16*64*128*4
static constexpr size_t OFF_ACTX      = 88604672;   // 10240*256*4
static constexpr size_t OFF_AOPT      = 99090432;   // 5120*256*4
static constexpr size_t OFF_MCTX      = 104333312;  // 80*512*4
static constexpr size_t OFF_MOPT      = 104497152;
static constexpr size_t WS_NEED       = 104660992;

extern "C" void kernel_launch(void* const* d_in, const int* in_sizes, int n_in,
                              void* d_out, int out_size, void* d_ws, size_t ws_size,
                              hipStream_t stream)
{
  (void)in_sizes; (void)n_in; (void)out_size;
  if (ws_size < WS_NEED) return;

  const float* context = (const float*)d_in[0];
  const float* options = (const float*)d_in[2];
  const float* rWi_f = (const float*)d_in[4];
  const float* rWh_f = (const float*)d_in[5];
  const float* rbi_f = (const float*)d_in[6];
  const float* rbh_f = (const float*)d_in[7];
  const float* rWi_b = (const float*)d_in[8];
  const float* rWh_b = (const float*)d_in[9];
  const float* rbi_b = (const float*)d_in[10];
  const float* rbh_b = (const float*)d_in[11];
  const float* aWi_f = (const float*)d_in[12];
  const float* aWh_f = (const float*)d_in[13];
  const float* abi_f = (const float*)d_in[14];
  const float* abh_f = (const float*)d_in[15];
  const float* aWi_b = (const float*)d_in[16];
  const float* aWh_b = (const float*)d_in[17];
  const float* abi_b = (const float*)d_in[18];
  const float* abh_b = (const float*)d_in[19];
  const float* Wk    = (const float*)d_in[20];
  const float* Wq    = (const float*)d_in[21];
  const float* vE    = (const float*)d_in[22];

  char* ws = (char*)d_ws;
  short* xp_ctx_f  = (short*)(ws + OFF_XP_CTX_F);
  short* xp_ctx_b  = (short*)(ws + OFF_XP_CTX_B);
  short* xp_opt_f  = (short*)(ws + OFF_XP_OPT_F);
  short* xp_opt_b  = (short*)(ws + OFF_XP_OPT_B);
  short* axp_ctx_f = (short*)(ws + OFF_AXP_CTX_F);
  short* axp_ctx_b = (short*)(ws + OFF_AXP_CTX_B);
  short* axp_opt_f = (short*)(ws + OFF_AXP_OPT_F);
  short* axp_opt_b = (short*)(ws + OFF_AXP_OPT_B);
  float* ctx_enc   = (float*)(ws + OFF_CTX_ENC);
  float* opt_enc   = (float*)(ws + OFF_OPT_ENC);
  float* att_enc_c = (float*)(ws + OFF_ATT_ENC_C);
  float* att_enc_o = (float*)(ws + OFF_ATT_ENC_O);
  float* ctx_key   = (float*)(ws + OFF_CTX_KEY);
  float* opt_q     = (float*)(ws + OFF_OPT_Q);
  float* e_all     = (float*)(ws + OFF_E);
  float* a_ctx     = (float*)(ws + OFF_ACTX);
  float* a_opt     = (float*)(ws + OFF_AOPT);
  float* m_ctx     = (float*)(ws + OFF_MCTX);
  float* m_opt     = (float*)(ws + OFF_MOPT);

  dim3 blk256(256), blk1024(1024), blk512(512);

  // L1: input projections (rows: ctx = b*128+t; opt = b*320+o*64+t)
  gemm_k<<<dim3(12, 32), blk256, 0, stream>>>(context, rWi_f, rbi_f, xp_ctx_f, 2048, 768, 300, 1);
  gemm_k<<<dim3(12, 32), blk256, 0, stream>>>(context, rWi_b, rbi_b, xp_ctx_b, 2048, 768, 300, 1);
  gemm_k<<<dim3(12, 80), blk256, 0, stream>>>(options, rWi_f, rbi_f, xp_opt_f, 5120, 768, 300, 1);
  gemm_k<<<dim3(12, 80), blk256, 0, stream>>>(options, rWi_b, rbi_b, xp_opt_b, 5120, 768, 300, 1);
  // L2: rnn scans (1 ctx chain + 5 opt chains, x2 directions, one block each)
  gru_scan_k<<<12, blk1024, 0, stream>>>(2, 128, 128, 0, xp_ctx_f, xp_ctx_b, ctx_enc,
                                         64, 320, 64, xp_opt_f, xp_opt_b, opt_enc,
                                         rWh_f, rWh_b, rbh_f, rbh_b);
  // L3: key / query projections
  gemm_k<<<dim3(4, 32), blk256, 0, stream>>>(ctx_enc, Wk, nullptr, ctx_key, 2048, 256, 512, 0);
  gemm_k<<<dim3(4, 80), blk256, 0, stream>>>(opt_enc, Wq, nullptr, opt_q, 5120, 256, 512, 0);
  // L4: additive energies
  energy_k<<<1280, blk256, 0, stream>>>(opt_q, ctx_key, vE, e_all);
  // L5: softmaxes + aggregations
  actx_k<<<10240, blk256, 0, stream>>>(e_all, opt_q, a_ctx);
  aopt_k<<<5120, blk256, 0, stream>>>(e_all, ctx_key, a_opt);
  // L6: attention-GRU input projections
  gemm_k<<<dim3(12, 160), blk256, 0, stream>>>(a_ctx, aWi_f, abi_f, axp_ctx_f, 10240, 768, 256, 1);
  gemm_k<<<dim3(12, 160), blk256, 0, stream>>>(a_ctx, aWi_b, abi_b, axp_ctx_b, 10240, 768, 256, 1);
  gemm_k<<<dim3(12, 80),  blk256, 0, stream>>>(a_opt, aWi_f, abi_f, axp_opt_f, 5120, 768, 256, 1);
  gemm_k<<<dim3(12, 80),  blk256, 0, stream>>>(a_opt, aWi_b, abi_b, axp_opt_b, 5120, 768, 256, 1);
  // L7: attention-GRU scans
  gru_scan_k<<<20, blk1024, 0, stream>>>(10, 128, 128, 2048, axp_ctx_f, axp_ctx_b, att_enc_c,
                                         64, 64, 1024, axp_opt_f, axp_opt_b, att_enc_o,
                                         aWh_f, aWh_b, abh_f, abh_b);
  // L8: temporal means
  mean_k<<<80, blk512, 0, stream>>>(att_enc_c, m_ctx, 128);
  mean_k<<<80, blk512, 0, stream>>>(att_enc_o, m_opt, 64);
  // L9: cosine + softmax over options
  final_k<<<1, blk512, 0, stream>>>(m_ctx, m_opt, (float*)d_out);
}

// Round 11
// 1306.861 us; speedup vs baseline: 1.2058x; 1.2058x over previous
//
#include <hip/hip_runtime.h>
#include <cstdint>
#include <cstddef>

#define LOG2E 1.4426950408889634f

using f32x4 = __attribute__((ext_vector_type(4))) float;
using s16x8 = __attribute__((ext_vector_type(8))) short;
using s16x4 = __attribute__((ext_vector_type(4))) short;

__device__ __forceinline__ short f2bf(float f){
  unsigned u = __builtin_bit_cast(unsigned, f);
  u = u + 0x7FFFu + ((u >> 16) & 1u);          // RNE
  return (short)(u >> 16);
}
__device__ __forceinline__ float bf2f(short s){
  unsigned u = ((unsigned)(unsigned short)s) << 16;
  return __builtin_bit_cast(float, u);
}
__device__ __forceinline__ float fexp2(float x){ return __builtin_amdgcn_exp2f(x); }
__device__ __forceinline__ float frcp (float x){ return __builtin_amdgcn_rcpf(x); }
__device__ __forceinline__ float sigmoid_f(float x){
  return frcp(1.f + fexp2(-LOG2E * x));
}
__device__ __forceinline__ float tanh_f(float x){
  return 1.f - 2.f * frcp(fexp2(2.f * LOG2E * x) + 1.f);
}

#define MFMA16(a,b,c) __builtin_amdgcn_mfma_f32_16x16x32_bf16(a,b,c,0,0,0)

// ---------------- GEMM: C[M,N] = A[M,K] @ W[N,K]^T (+bias), bf16 MFMA ----------------
__global__ __launch_bounds__(256) void gemm_k(
    const float* __restrict__ A, const float* __restrict__ W,
    const float* __restrict__ bias, void* __restrict__ Cout,
    int M, int N, int K, int outBf16)
{
  __shared__ short As[64*40];
  __shared__ short Ws[64*40];
  const int tid  = threadIdx.x;
  const int lane = tid & 63;
  const int wave = tid >> 6;
  const int wm   = wave >> 1, wn = wave & 1;
  const int c    = lane & 15, rg = lane >> 4;
  const int bm   = blockIdx.y * 64, bn = blockIdx.x * 64;
  const int K4   = K >> 2;
  const int nkt  = (K + 31) >> 5;
  f32x4 acc[2][2] = {};
  for (int kt = 0; kt < nkt; ++kt){
    #pragma unroll
    for (int h = 0; h < 2; ++h){
      int idx = tid + h*256;
      int row = idx >> 3, q = idx & 7;
      int kq  = kt*8 + q;
      f32x4 av = {0.f,0.f,0.f,0.f}, wv4 = {0.f,0.f,0.f,0.f};
      if (kq < K4){
        av  = *(const f32x4*)(A + (size_t)(bm+row)*K + (size_t)kq*4);
        wv4 = *(const f32x4*)(W + (size_t)(bn+row)*K + (size_t)kq*4);
      }
      s16x4 ap, wp;
      #pragma unroll
      for (int i = 0; i < 4; ++i){ ap[i] = f2bf(av[i]); wp[i] = f2bf(wv4[i]); }
      *(s16x4*)&As[row*40 + q*4] = ap;
      *(s16x4*)&Ws[row*40 + q*4] = wp;
    }
    __syncthreads();
    s16x8 af[2], bf[2];
    #pragma unroll
    for (int mi = 0; mi < 2; ++mi) af[mi] = *(const s16x8*)&As[(wm*32 + mi*16 + c)*40 + rg*8];
    #pragma unroll
    for (int ni = 0; ni < 2; ++ni) bf[ni] = *(const s16x8*)&Ws[(wn*32 + ni*16 + c)*40 + rg*8];
    #pragma unroll
    for (int mi = 0; mi < 2; ++mi)
      #pragma unroll
      for (int ni = 0; ni < 2; ++ni)
        acc[mi][ni] = MFMA16(af[mi], bf[ni], acc[mi][ni]);
    __syncthreads();
  }
  #pragma unroll
  for (int mi = 0; mi < 2; ++mi)
    #pragma unroll
    for (int ni = 0; ni < 2; ++ni)
      #pragma unroll
      for (int i = 0; i < 4; ++i){
        int row = bm + wm*32 + mi*16 + rg*4 + i;
        int col = bn + wn*32 + ni*16 + c;
        float v = acc[mi][ni][i] + (bias ? bias[col] : 0.f);
        if (outBf16) ((short*)Cout)[(size_t)row*N + col] = f2bf(v);
        else         ((float*)Cout)[(size_t)row*N + col] = v;
      }
}

// ---------------- pack Wh fp32 [768][256] -> bf16 MFMA B-fragment order ----------------
// dst[((cb*3+g)*8+kb)*512 + lane*8 + e] = bf16(W[g*256 + cb*16 + (lane&15)][kb*32 + (lane>>4)*8 + e])
// One fragment = 512 shorts = 1KB, lane-contiguous -> global_load_dwordx4 per lane is coalesced.
__global__ __launch_bounds__(512) void packw_k(
    const float* __restrict__ Wf, const float* __restrict__ Wb,
    short* __restrict__ Df, short* __restrict__ Db)
{
  const float* S = blockIdx.y ? Wb : Wf;
  short*       D = blockIdx.y ? Db : Df;
  const int bx = blockIdx.x;            // cb*3+g, 0..47
  const int cb = bx / 3, g = bx - cb*3;
  const int t = threadIdx.x;
  const int kb = t >> 6, lane = t & 63;
  const float* sp = S + (size_t)(g*256 + cb*16 + (lane & 15))*256 + kb*32 + (lane >> 4)*8;
  short* dp = D + ((size_t)bx*8 + kb)*512 + lane*8;
  #pragma unroll
  for (int e = 0; e < 8; ++e) dp[e] = f2bf(sp[e]);
}

// ---------------- GRU scan: one block per (chain, direction), 8 waves ----------------
// Wave w owns col-blocks {w, w+8}: cols j=(w+8*cb)*16+c, all 3 gates. Weights are NOT
// held in registers (compiler caps VGPR and spills large arrays -> scratch reload was
// the r2..r9 bottleneck). Instead each fragment is streamed per step from the packed
// bf16 buffer (L2-resident, coalesced 1KB/frag); the compiler pipelines loads under
// the 128-VGPR cap. xp double-buffered in LDS via global_load_lds prefetch; h fp32 in
// regs; bf16 h copy XOR-swizzled in LDS for MFMA A-fragments.
__global__ __launch_bounds__(512, 2) void gru_scan_k(
    int nA, int TA, int sBA, int bMA,
    const short* __restrict__ xpfA, const short* __restrict__ xpbA, float* __restrict__ outA,
    int TB, int sBB, int bMB,
    const short* __restrict__ xpfB, const short* __restrict__ xpbB, float* __restrict__ outB,
    const short* __restrict__ wpkf, const short* __restrict__ wpkb,
    const float* __restrict__ bhf, const float* __restrict__ bhb)
{
  __shared__ short h_bf[16*256];     // (b,k) at b*256 + (k ^ ((b&7)<<3))
  __shared__ short xp_s[2][16*768];  // double-buffered [b][n] bf16

  const int tid  = threadIdx.x;
  const int w    = tid >> 6;          // 0..7
  const int lane = tid & 63;
  const int c    = lane & 15;
  const int rg   = lane >> 4;

  int T, strideB, baseRow, dir;
  const short* xp; float* outp;
  const short* wpk; const float* bh;
  {
    int bid = blockIdx.x;
    if (bid < nA){
      int idx = bid >> 1; dir = bid & 1;
      T = TA; strideB = sBA; baseRow = idx * bMA;
      xp = dir ? xpbA : xpfA; outp = outA;
    } else {
      int jj = bid - nA; int idx = jj >> 1; dir = jj & 1;
      T = TB; strideB = sBB; baseRow = idx * bMB;
      xp = dir ? xpbB : xpfB; outp = outB;
    }
    wpk = dir ? wpkb : wpkf;
    bh  = dir ? bhb  : bhf;
  }

  #pragma unroll
  for (int i = 0; i < 8; ++i) h_bf[tid*8 + i] = 0;

  // per-wave packed-weight bases (cb0 = w, cb1 = w+8), lane offset folded in
  const short* wp0 = wpk + (size_t)w      * 12288 + lane*8;   // 3*8*512 = 12288
  const short* wp1 = wpk + (size_t)(w + 8) * 12288 + lane*8;

  // bias constants -> 6 regs
  float bhc[2][3];
  #pragma unroll
  for (int cb = 0; cb < 2; ++cb){
    const int j = (w + 8*cb)*16 + c;
    bhc[cb][0] = bh[j]; bhc[cb][1] = bh[256 + j]; bhc[cb][2] = bh[512 + j];
  }

  auto stage = [&](int tt_, int buf){
    #pragma unroll
    for (int i2 = 0; i2 < 3; ++i2){
      int idx8 = tid + 512*i2;            // 8-short units, 1536 total
      int row  = idx8 / 96;
      int u    = idx8 - row*96;
      const short* src = xp + (size_t)(baseRow + row*strideB + tt_)*768 + u*8;
      __builtin_amdgcn_global_load_lds((const __attribute__((address_space(1))) void*)src,
                                       (__attribute__((address_space(3))) void*)&xp_s[buf][idx8*8],
                                       16, 0, 0);
    }
  };

  float hprev[2][4] = {};
  stage(dir ? (T - 1) : 0, 0);
  __syncthreads();                        // xp buf0 ready; h_bf zeros visible

  for (int t = 0; t < T; ++t){
    const int cur = t & 1;
    if (t + 1 < T) stage(dir ? (T - 2 - t) : (t + 1), cur ^ 1);   // prefetch next step
    const int tt = dir ? (T - 1 - t) : t;

    f32x4 acc[2][3];
    #pragma unroll
    for (int cb = 0; cb < 2; ++cb)
      #pragma unroll
      for (int g = 0; g < 3; ++g) acc[cb][g] = (f32x4){0.f,0.f,0.f,0.f};

    #pragma unroll
    for (int kb = 0; kb < 8; ++kb){
      const int k0 = kb*32 + rg*8;
      const s16x8 a = *(const s16x8*)&h_bf[c*256 + (k0 ^ ((c & 7) << 3))];
      #pragma unroll
      for (int g = 0; g < 3; ++g){
        const s16x8 w0 = *(const s16x8*)(wp0 + (g*8 + kb)*512);
        const s16x8 w1 = *(const s16x8*)(wp1 + (g*8 + kb)*512);
        acc[0][g] = MFMA16(a, w0, acc[0][g]);
        acc[1][g] = MFMA16(a, w1, acc[1][g]);
      }
    }

    float hnew[2][4];
    const short* xrow = &xp_s[cur][0];
    #pragma unroll
    for (int cb = 0; cb < 2; ++cb){
      const int j = (w + 8*cb)*16 + c;
      #pragma unroll
      for (int i = 0; i < 4; ++i){
        const int b = rg*4 + i;           // D: row=(l>>4)*4+reg = batch
        const float xr = bf2f(xrow[b*768 + j]);
        const float xz = bf2f(xrow[b*768 + 256 + j]);
        const float xn = bf2f(xrow[b*768 + 512 + j]);
        float r = sigmoid_f(acc[cb][0][i] + bhc[cb][0] + xr);
        float z = sigmoid_f(acc[cb][1][i] + bhc[cb][1] + xz);
        float n = tanh_f(xn + r*(acc[cb][2][i] + bhc[cb][2]));
        float h = n + z*(hprev[cb][i] - n);
        hprev[cb][i] = h; hnew[cb][i] = h;
        outp[(size_t)(baseRow + b*strideB + tt)*512 + (size_t)dir*256 + j] = h;
      }
    }
    __syncthreads();                      // all h_bf reads done (also drains prefetch vmcnt)
    #pragma unroll
    for (int cb = 0; cb < 2; ++cb){
      const int j = (w + 8*cb)*16 + c;
      #pragma unroll
      for (int i = 0; i < 4; ++i){
        const int b = rg*4 + i;
        h_bf[b*256 + (j ^ ((b & 7) << 3))] = f2bf(hnew[cb][i]);
      }
    }
    __syncthreads();                      // new h visible to all waves
  }
}

// ---------------- Bahdanau energies: e[o,b,q,c] = sum_h tanh(oq+ck)*v ----------------
__global__ __launch_bounds__(256) void energy_k(
    const float* __restrict__ oq, const float* __restrict__ ck,
    const float* __restrict__ v, float* __restrict__ e)
{
  __shared__ float oqs[4][256];
  __shared__ float vs[256];
  const int bid = blockIdx.x;          // 1280 = 5 o * 16 b * 16 qg
  const int o  = bid >> 8;
  const int b  = (bid >> 4) & 15;
  const int qg = bid & 15;
  const int tid = threadIdx.x;
  const int wv = tid >> 6, lane = tid & 63;
  const int q = qg*4 + wv;
  vs[tid] = v[tid];
  const float* oqrow = oq + (size_t)((b*5 + o)*64 + q)*256;
  #pragma unroll
  for (int i = 0; i < 4; ++i) oqs[wv][lane + i*64] = oqrow[lane + i*64];
  __syncthreads();
  float acc0 = 0.f, acc1 = 0.f;
  const float* ckb = ck + (size_t)b*128*256;
  for (int h = 0; h < 256; ++h){
    float t  = oqs[wv][h];
    float vh = vs[h];
    acc0 += tanh_f(t + ckb[(size_t)lane*256 + h]) * vh;
    acc1 += tanh_f(t + ckb[(size_t)(lane+64)*256 + h]) * vh;
  }
  const size_t ebase = (size_t)((o*16 + b)*64 + q)*128;
  e[ebase + lane]      = acc0;
  e[ebase + lane + 64] = acc1;
}

// softmax over q (64) + a_ctx[o,b,c,h] = sum_q w_q * oq[b,o,q,h]
__global__ __launch_bounds__(256) void actx_k(
    const float* __restrict__ e, const float* __restrict__ oq, float* __restrict__ a_ctx)
{
  __shared__ float wq[64];
  const int bid = blockIdx.x;          // 10240 = 5 o * 16 b * 128 c
  const int o  = bid >> 11;
  const int b  = (bid >> 7) & 15;
  const int cc = bid & 127;
  const int tid = threadIdx.x;
  if (tid < 64){
    float x = e[((size_t)((o*16 + b)*64 + tid))*128 + cc];
    float mx = x;
    #pragma unroll
    for (int off = 32; off; off >>= 1) mx = fmaxf(mx, __shfl_xor(mx, off));
    float p = fexp2((x - mx)*LOG2E);
    float sm = p;
    #pragma unroll
    for (int off = 32; off; off >>= 1) sm += __shfl_xor(sm, off);
    wq[tid] = p * frcp(sm);
  }
  __syncthreads();
  float acc = 0.f;
  const float* oqb = oq + ((size_t)(b*320 + o*64))*256 + tid;
  #pragma unroll 4
  for (int q = 0; q < 64; ++q) acc += wq[q] * oqb[(size_t)q*256];
  a_ctx[((size_t)((o*16 + b)*128 + cc))*256 + tid] = acc;
}

// softmax over c (128) + a_opt[o,b,q,h] = sum_c w_c * ck[b,c,h]
__global__ __launch_bounds__(256) void aopt_k(
    const float* __restrict__ e, const float* __restrict__ ck, float* __restrict__ a_opt)
{
  __shared__ float wc[128];
  __shared__ float red[4];
  const int bid = blockIdx.x;          // 5120 = 5 o * 16 b * 64 q
  const int o = bid >> 10;
  const int b = (bid >> 6) & 15;
  const int q = bid & 63;
  const int tid = threadIdx.x, lane = tid & 63, wv = tid >> 6;
  const float* er = e + ((size_t)((o*16 + b)*64 + q))*128;
  float x = (tid < 128) ? er[tid] : -3.0e38f;
  float mx = x;
  #pragma unroll
  for (int off = 32; off; off >>= 1) mx = fmaxf(mx, __shfl_xor(mx, off));
  if (lane == 0 && wv < 2) red[wv] = mx;
  __syncthreads();
  float gm = fmaxf(red[0], red[1]);
  float p = (tid < 128) ? fexp2((x - gm)*LOG2E) : 0.f;
  float sm = p;
  #pragma unroll
  for (int off = 32; off; off >>= 1) sm += __shfl_xor(sm, off);
  if (lane == 0 && wv < 2) red[2 + wv] = sm;
  __syncthreads();
  float tot = red[2] + red[3];
  if (tid < 128) wc[tid] = p * frcp(tot);
  __syncthreads();
  float acc = 0.f;
  const float* ckb = ck + (size_t)b*128*256 + tid;
  #pragma unroll 4
  for (int cc = 0; cc < 128; ++cc) acc += wc[cc] * ckb[(size_t)cc*256];
  a_opt[((size_t)((o*16 + b)*64 + q))*256 + tid] = acc;
}

// mean over T rows of 512: 8 independent accumulators -> 8 loads in flight
__global__ __launch_bounds__(512) void mean_k(
    const float* __restrict__ src, float* __restrict__ dst, int T)
{
  const int r = blockIdx.x;            // 80 = (o*16+b)
  const int f = threadIdx.x;
  const float* s = src + (size_t)r*T*512 + f;
  float a0=0.f,a1=0.f,a2=0.f,a3=0.f,a4=0.f,a5=0.f,a6=0.f,a7=0.f;
  for (int t = 0; t < T; t += 8){
    a0 += s[(size_t)(t+0)*512]; a1 += s[(size_t)(t+1)*512];
    a2 += s[(size_t)(t+2)*512]; a3 += s[(size_t)(t+3)*512];
    a4 += s[(size_t)(t+4)*512]; a5 += s[(size_t)(t+5)*512];
    a6 += s[(size_t)(t+6)*512]; a7 += s[(size_t)(t+7)*512];
  }
  float acc = ((a0+a1)+(a2+a3)) + ((a4+a5)+(a6+a7));
  dst[(size_t)r*512 + f] = acc / (float)T;
}

__global__ __launch_bounds__(512) void final_k(
    const float* __restrict__ mc, const float* __restrict__ mo, float* __restrict__ out)
{
  __shared__ float lg[80];
  const int tid = threadIdx.x;
  const int wv = tid >> 6, lane = tid & 63;
  #pragma unroll
  for (int it = 0; it < 10; ++it){
    const int p = wv + it*8;
    const float* a = mc + (size_t)p*512;
    const float* b = mo + (size_t)p*512;
    float d = 0.f, na = 0.f, nb = 0.f;
    #pragma unroll
    for (int i = 0; i < 8; ++i){
      float x = a[lane + 64*i], y = b[lane + 64*i];
      d += x*y; na += x*x; nb += y*y;
    }
    #pragma unroll
    for (int off = 32; off; off >>= 1){
      d += __shfl_xor(d, off); na += __shfl_xor(na, off); nb += __shfl_xor(nb, off);
    }
    if (lane == 0){
      float den = fmaxf(sqrtf(na), 1e-8f) * fmaxf(sqrtf(nb), 1e-8f);
      lg[p] = d / den;
    }
  }
  __syncthreads();
  if (tid < 16){
    float l[5];
    float mx = -3.0e38f;
    #pragma unroll
    for (int o = 0; o < 5; ++o){ l[o] = lg[o*16 + tid]; mx = fmaxf(mx, l[o]); }
    float s = 0.f;
    #pragma unroll
    for (int o = 0; o < 5; ++o){ l[o] = fexp2((l[o]-mx)*LOG2E); s += l[o]; }
    #pragma unroll
    for (int o = 0; o < 5; ++o) out[tid*5 + o] = l[o] / s;
  }
}

// ---------------- workspace layout (bytes, all offsets 256-aligned) ----------------
static constexpr size_t OFF_XP_CTX_F  = 0;          // 2048*768*2  = 3,145,728
static constexpr size_t OFF_XP_CTX_B  = 3145728;
static constexpr size_t OFF_XP_OPT_F  = 6291456;    // 5120*768*2  = 7,864,320
static constexpr size_t OFF_XP_OPT_B  = 14155776;
static constexpr size_t OFF_AXP_CTX_F = 0;          // 10240*768*2 = 15,728,640
static constexpr size_t OFF_AXP_CTX_B = 15728640;
static constexpr size_t OFF_AXP_OPT_F = 31457280;   // 5120*768*2
static constexpr size_t OFF_AXP_OPT_B = 39321600;
static constexpr size_t REGION_B      = 47185920;
static constexpr size_t OFF_CTX_ENC   = REGION_B;               // 2048*512*4
static constexpr size_t OFF_OPT_ENC   = REGION_B + 4194304;     // 5120*512*4
static constexpr size_t OFF_ATT_ENC_C = REGION_B;               // 10240*512*4
static constexpr size_t OFF_ATT_ENC_O = REGION_B + 20971520;    // 5120*512*4
static constexpr size_t OFF_CTX_KEY   = 78643200;   // 2048*256*4
static constexpr size_t OFF_OPT_Q     = 80740352;   // 5120*256*4
static constexpr size_t OFF_E         = 85983232;   // 5*16*64*128*4 = 2,621,440
// packed weights alias the e_all window (disjoint lifetimes):
//   rnn pack written before L2, consumed by L2 (e_all first written at L4)
//   att pack written after L5 (last e_all read), consumed by L7
static constexpr size_t OFF_WPK_F     = OFF_E;              // 196,608 B
static constexpr size_t OFF_WPK_B     = OFF_E + 196608;     // 196,608 B
static constexpr size_t OFF_ACTX      = 88604672;   // 10240*256*4
static constexpr size_t OFF_AOPT      = 99090432;   // 5120*256*4
static constexpr size_t OFF_MCTX      = 104333312;  // 80*512*4
static constexpr size_t OFF_MOPT      = 104497152;
static constexpr size_t WS_NEED       = 104660992;

extern "C" void kernel_launch(void* const* d_in, const int* in_sizes, int n_in,
                              void* d_out, int out_size, void* d_ws, size_t ws_size,
                              hipStream_t stream)
{
  (void)in_sizes; (void)n_in; (void)out_size;
  if (ws_size < WS_NEED) return;

  const float* context = (const float*)d_in[0];
  const float* options = (const float*)d_in[2];
  const float* rWi_f = (const float*)d_in[4];
  const float* rWh_f = (const float*)d_in[5];
  const float* rbi_f = (const float*)d_in[6];
  const float* rbh_f = (const float*)d_in[7];
  const float* rWi_b = (const float*)d_in[8];
  const float* rWh_b = (const float*)d_in[9];
  const float* rbi_b = (const float*)d_in[10];
  const float* rbh_b = (const float*)d_in[11];
  const float* aWi_f = (const float*)d_in[12];
  const float* aWh_f = (const float*)d_in[13];
  const float* abi_f = (const float*)d_in[14];
  const float* abh_f = (const float*)d_in[15];
  const float* aWi_b = (const float*)d_in[16];
  const float* aWh_b = (const float*)d_in[17];
  const float* abi_b = (const float*)d_in[18];
  const float* abh_b = (const float*)d_in[19];
  const float* Wk    = (const float*)d_in[20];
  const float* Wq    = (const float*)d_in[21];
  const float* vE    = (const float*)d_in[22];

  char* ws = (char*)d_ws;
  short* xp_ctx_f  = (short*)(ws + OFF_XP_CTX_F);
  short* xp_ctx_b  = (short*)(ws + OFF_XP_CTX_B);
  short* xp_opt_f  = (short*)(ws + OFF_XP_OPT_F);
  short* xp_opt_b  = (short*)(ws + OFF_XP_OPT_B);
  short* axp_ctx_f = (short*)(ws + OFF_AXP_CTX_F);
  short* axp_ctx_b = (short*)(ws + OFF_AXP_CTX_B);
  short* axp_opt_f = (short*)(ws + OFF_AXP_OPT_F);
  short* axp_opt_b = (short*)(ws + OFF_AXP_OPT_B);
  float* ctx_enc   = (float*)(ws + OFF_CTX_ENC);
  float* opt_enc   = (float*)(ws + OFF_OPT_ENC);
  float* att_enc_c = (float*)(ws + OFF_ATT_ENC_C);
  float* att_enc_o = (float*)(ws + OFF_ATT_ENC_O);
  float* ctx_key   = (float*)(ws + OFF_CTX_KEY);
  float* opt_q     = (float*)(ws + OFF_OPT_Q);
  float* e_all     = (float*)(ws + OFF_E);
  short* wpk_f     = (short*)(ws + OFF_WPK_F);
  short* wpk_b     = (short*)(ws + OFF_WPK_B);
  float* a_ctx     = (float*)(ws + OFF_ACTX);
  float* a_opt     = (float*)(ws + OFF_AOPT);
  float* m_ctx     = (float*)(ws + OFF_MCTX);
  float* m_opt     = (float*)(ws + OFF_MOPT);

  dim3 blk256(256), blk512(512);

  // L0: pack rnn recurrent weights (bf16 fragment order) into the e_all alias window
  packw_k<<<dim3(48, 2), blk512, 0, stream>>>(rWh_f, rWh_b, wpk_f, wpk_b);
  // L1: input projections (rows: ctx = b*128+t; opt = b*320+o*64+t)
  gemm_k<<<dim3(12, 32), blk256, 0, stream>>>(context, rWi_f, rbi_f, xp_ctx_f, 2048, 768, 300, 1);
  gemm_k<<<dim3(12, 32), blk256, 0, stream>>>(context, rWi_b, rbi_b, xp_ctx_b, 2048, 768, 300, 1);
  gemm_k<<<dim3(12, 80), blk256, 0, stream>>>(options, rWi_f, rbi_f, xp_opt_f, 5120, 768, 300, 1);
  gemm_k<<<dim3(12, 80), blk256, 0, stream>>>(options, rWi_b, rbi_b, xp_opt_b, 5120, 768, 300, 1);
  // L2: rnn scans (1 ctx chain + 5 opt chains, x2 directions, one block each)
  gru_scan_k<<<12, blk512, 0, stream>>>(2, 128, 128, 0, xp_ctx_f, xp_ctx_b, ctx_enc,
                                        64, 320, 64, xp_opt_f, xp_opt_b, opt_enc,
                                        wpk_f, wpk_b, rbh_f, rbh_b);
  // L3: key / query projections
  gemm_k<<<dim3(4, 32), blk256, 0, stream>>>(ctx_enc, Wk, nullptr, ctx_key, 2048, 256, 512, 0);
  gemm_k<<<dim3(4, 80), blk256, 0, stream>>>(opt_enc, Wq, nullptr, opt_q, 5120, 256, 512, 0);
  // L4: additive energies (overwrites nothing of wpk until L5 done -> wpk_rnn dead now)
  energy_k<<<1280, blk256, 0, stream>>>(opt_q, ctx_key, vE, e_all);
  // L5: softmaxes + aggregations
  actx_k<<<10240, blk256, 0, stream>>>(e_all, opt_q, a_ctx);
  aopt_k<<<5120, blk256, 0, stream>>>(e_all, ctx_key, a_opt);
  // L5b: e_all now dead -> pack att recurrent weights into the same window
  packw_k<<<dim3(48, 2), blk512, 0, stream>>>(aWh_f, aWh_b, wpk_f, wpk_b);
  // L6: attention-GRU input projections
  gemm_k<<<dim3(12, 160), blk256, 0, stream>>>(a_ctx, aWi_f, abi_f, axp_ctx_f, 10240, 768, 256, 1);
  gemm_k<<<dim3(12, 160), blk256, 0, stream>>>(a_ctx, aWi_b, abi_b, axp_ctx_b, 10240, 768, 256, 1);
  gemm_k<<<dim3(12, 80),  blk256, 0, stream>>>(a_opt, aWi_f, abi_f, axp_opt_f, 5120, 768, 256, 1);
  gemm_k<<<dim3(12, 80),  blk256, 0, stream>>>(a_opt, aWi_b, abi_b, axp_opt_b, 5120, 768, 256, 1);
  // L7: attention-GRU scans
  gru_scan_k<<<20, blk512, 0, stream>>>(10, 128, 128, 2048, axp_ctx_f, axp_ctx_b, att_enc_c,
                                        64, 64, 1024, axp_opt_f, axp_opt_b, att_enc_o,
                                        wpk_f, wpk_b, abh_f, abh_b);
  // L8: temporal means
  mean_k<<<80, blk512, 0, stream>>>(att_enc_c, m_ctx, 128);
  mean_k<<<80, blk512, 0, stream>>>(att_enc_o, m_opt, 64);
  // L9: cosine + softmax over options
  final_k<<<1, blk512, 0, stream>>>(m_ctx, m_opt, (float*)d_out);
}